// Round 1
// baseline (65.265 us; speedup 1.0000x reference)
//
#include <hip/hip_runtime.h>
#include <math.h>

// PQC_26757646254573
//
// Analytical structure: out_b = exp(f1_b + i*f2_b) with
//   f_b = D[idx_last, idx_b]  if idx_last < 8, else 0
// where idx_last is the bit-pattern of sign(x[-1]). setup_inputs() forces
// x[-1] = |x[-1]|+1 > 0, so idx_last == 255 >= 8 -> c_shadow == 0 ->
// out == 1+0i everywhere. We still compute idx_last from x on device and
// implement the full general path (single-block fp64 fallback) so the kernel
// is correct for any input, but the live path is two tiny launches.

#define NQ 8
#define NL 6
#define QDIM 256
#define BATCH 16384

// workspace layout in doubles:
//   U : QDIM*QDIM complex -> 131072 doubles
//   T : 131072
//   R : 131072
//   v : 2 circuits * 256 doubles
#define OFF_U 0
#define OFF_T 131072
#define OFF_R 262144
#define OFF_V 393216

__device__ __forceinline__ int compute_idx(const float* __restrict__ xrow) {
  int v = 0;
#pragma unroll
  for (int j = 0; j < NQ; ++j)
    v |= (xrow[j] > 0.0f) ? (1 << (NQ - 1 - j)) : 0;
  return v;
}

// General-path fallback: one block, 256 threads; thread t owns row t of U.
// Chain: U = I; for l: for n in 0..6: U = U@C_n; U = U@r_l;  then U = U@H.
// Only runs when idx_last < 8 (never with the harness inputs).
__global__ __launch_bounds__(256) void heavy_kernel(
    const float* __restrict__ x,
    const float* __restrict__ qx1, const float* __restrict__ qz1,
    const float* __restrict__ qx2, const float* __restrict__ qz2,
    double* __restrict__ W)
{
  const int idxl = compute_idx(x + (size_t)(BATCH - 1) * NQ);
  if (idxl >= NQ) return;  // live path: c_shadow == 0, nothing to compute

  const int t = threadIdx.x;  // 0..255 = row of U owned by this thread
  double* U = W + OFF_U;
  double* T = W + OFF_T;
  double* R = W + OFF_R;
  const double ainv = 0.8705505632961241;  // 2^-0.2

  for (int circ = 0; circ < 2; ++circ) {
    const float* qx = circ ? qx2 : qx1;
    const float* qz = circ ? qz2 : qz1;

    // U = I  (row t)
    for (int c = 0; c < QDIM; ++c) {
      U[((size_t)t * QDIM + c) * 2 + 0] = (c == t) ? 1.0 : 0.0;
      U[((size_t)t * QDIM + c) * 2 + 1] = 0.0;
    }

    for (int l = 0; l < NL; ++l) {
      // per-qubit 2x2 M = Rz(qz) @ Rx(qx)
      double Mr[NQ][2][2], Mi[NQ][2][2];
      for (int j = 0; j < NQ; ++j) {
        double hx = 0.5 * (double)qx[l * NQ + j];
        double hz = 0.5 * (double)qz[l * NQ + j];
        double cx = cos(hx), sx = sin(hx), cz = cos(hz), sz = sin(hz);
        Mr[j][0][0] =  cx * cz;  Mi[j][0][0] =  cx * sz;   // cx*(cz+i sz)
        Mr[j][0][1] = -sx * sz;  Mi[j][0][1] =  sx * cz;   // i sx*(cz+i sz)
        Mr[j][1][0] =  sx * sz;  Mi[j][1][0] =  sx * cz;   // i sx*(cz-i sz)
        Mr[j][1][1] =  cx * cz;  Mi[j][1][1] = -cx * sz;   // cx*(cz-i sz)
      }

      __syncthreads();  // all threads done reading previous layer's R
      // r_l row t: product over qubits of M[j][bit_j(t)][bit_j(c)]
      for (int c = 0; c < QDIM; ++c) {
        double ar = 1.0, ai = 0.0;
        for (int j = 0; j < NQ; ++j) {
          int rb = (t >> (NQ - 1 - j)) & 1;
          int cb = (c >> (NQ - 1 - j)) & 1;
          double br = Mr[j][rb][cb], bi = Mi[j][rb][cb];
          double nr = ar * br - ai * bi;
          ai = ar * bi + ai * br;
          ar = nr;
        }
        R[((size_t)t * QDIM + c) * 2 + 0] = ar;
        R[((size_t)t * QDIM + c) * 2 + 1] = ai;
      }
      __syncthreads();  // R fully built

      for (int n = 0; n < NQ - 1; ++n) {
        // U = U @ C_n. C = (I + i*s)/alpha with s = 2*(qubit n projector on |1>)
        // x (I-X on qubit n+1). Column op, row-local:
        //   bit_n(c)==0 : u[c] /= alpha
        //   bit_n(c)==1 : u[c]  = ((1+2i)u[c] - 2i u[c^fm]) / alpha  (paired)
        const int bn = NQ - 1 - n;        // bit position of qubit n
        const int fm = 1 << (NQ - 2 - n); // flip mask for qubit n+1
        for (int c = 0; c < QDIM; ++c) {
          size_t pc = ((size_t)t * QDIM + c) * 2;
          if (((c >> bn) & 1) == 0) {
            U[pc + 0] *= ainv;
            U[pc + 1] *= ainv;
          } else if ((c & fm) == 0) {
            int c2 = c | fm;
            size_t p2 = ((size_t)t * QDIM + c2) * 2;
            double ar = U[pc + 0], ai = U[pc + 1];
            double br = U[p2 + 0], bi = U[p2 + 1];
            U[pc + 0] = (ar - 2.0 * ai + 2.0 * bi) * ainv;
            U[pc + 1] = (ai + 2.0 * ar - 2.0 * br) * ainv;
            U[p2 + 0] = (br - 2.0 * bi + 2.0 * ai) * ainv;
            U[p2 + 1] = (bi + 2.0 * br - 2.0 * ar) * ainv;
          }
        }
        // U = U @ R (dense, row t): T_row = U_row * R; copy back
        for (int c = 0; c < QDIM; ++c) {
          double ar = 0.0, ai = 0.0;
          for (int k = 0; k < QDIM; ++k) {
            double ur = U[((size_t)t * QDIM + k) * 2 + 0];
            double ui = U[((size_t)t * QDIM + k) * 2 + 1];
            double rr = R[((size_t)k * QDIM + c) * 2 + 0];
            double ri = R[((size_t)k * QDIM + c) * 2 + 1];
            ar += ur * rr - ui * ri;
            ai += ur * ri + ui * rr;
          }
          T[((size_t)t * QDIM + c) * 2 + 0] = ar;
          T[((size_t)t * QDIM + c) * 2 + 1] = ai;
        }
        for (int c = 0; c < QDIM; ++c) {
          U[((size_t)t * QDIM + c) * 2 + 0] = T[((size_t)t * QDIM + c) * 2 + 0];
          U[((size_t)t * QDIM + c) * 2 + 1] = T[((size_t)t * QDIM + c) * 2 + 1];
        }
      }
    }

    // U = U @ H, H[k][c] = (1/16)*(-1)^popc(k&c)  -> into T
    for (int c = 0; c < QDIM; ++c) {
      double ar = 0.0, ai = 0.0;
      for (int k = 0; k < QDIM; ++k) {
        double s = (__popc(k & c) & 1) ? -1.0 : 1.0;
        ar += U[((size_t)t * QDIM + k) * 2 + 0] * s;
        ai += U[((size_t)t * QDIM + k) * 2 + 1] * s;
      }
      T[((size_t)t * QDIM + c) * 2 + 0] = ar * 0.0625;
      T[((size_t)t * QDIM + c) * 2 + 1] = ai * 0.0625;
    }
    __syncthreads();  // T fully built before column reduction

    // v[c=t] = sum_m (1 - 2*bit_{idxl}(m)) * |T[m, t]|^2
    {
      double acc = 0.0;
      for (int m = 0; m < QDIM; ++m) {
        double s = ((m >> (NQ - 1 - idxl)) & 1) ? -1.0 : 1.0;
        double re = T[((size_t)m * QDIM + t) * 2 + 0];
        double im = T[((size_t)m * QDIM + t) * 2 + 1];
        acc += s * (re * re + im * im);
      }
      W[OFF_V + circ * QDIM + t] = acc;
    }
    __syncthreads();  // done reading T before next circuit overwrites it
  }
}

__global__ __launch_bounds__(256) void out_kernel(
    const float* __restrict__ x, const double* __restrict__ W,
    float* __restrict__ out, int n_complex, int interleaved)
{
  int b = blockIdx.x * blockDim.x + threadIdx.x;
  if (b >= n_complex) return;

  // idx_last: same 8 floats for every thread -> cache-broadcast
  const int idxl = compute_idx(x + (size_t)(BATCH - 1) * NQ);

  float re = 1.0f, im = 0.0f;  // exp(0+0i) when c_shadow == 0
  if (idxl < NQ) {
    const int ib = compute_idx(x + (size_t)b * NQ);
    double f1 = W[OFF_V + 0 * QDIM + ib];
    double f2 = W[OFF_V + 1 * QDIM + ib];
    double e = exp(f1);
    re = (float)(e * cos(f2));
    im = (float)(e * sin(f2));
  }

  if (interleaved) {
    float2 v; v.x = re; v.y = im;
    reinterpret_cast<float2*>(out)[b] = v;
  } else {
    out[b] = re;
  }
}

extern "C" void kernel_launch(void* const* d_in, const int* in_sizes, int n_in,
                              void* d_out, int out_size, void* d_ws, size_t ws_size,
                              hipStream_t stream) {
  const float* x   = (const float*)d_in[0];
  const float* qx1 = (const float*)d_in[1];
  const float* qz1 = (const float*)d_in[2];
  const float* qx2 = (const float*)d_in[3];
  const float* qz2 = (const float*)d_in[4];
  // d_in[5], d_in[6] (c1, c2) are dead inputs in the reference (_f ignores c_embed)

  double* W  = (double*)d_ws;
  float* out = (float*)d_out;

  // General-path fallback: early-exits immediately when idx_last >= 8
  heavy_kernel<<<1, 256, 0, stream>>>(x, qx1, qz1, qx2, qz2, W);

  // complex128 output flattened as float32: assume interleaved (re,im) when
  // out_size == 2*BATCH; real-only layout otherwise
  const int interleaved = (out_size == 2 * BATCH) ? 1 : 0;
  const int n = interleaved ? (out_size / 2) : out_size;
  const int blocks = (n + 255) / 256;
  out_kernel<<<blocks, 256, 0, stream>>>(x, W, out, n, interleaved);
}

// Round 2
// 64.860 us; speedup vs baseline: 1.0062x; 1.0062x over previous
//
#include <hip/hip_runtime.h>
#include <math.h>

// PQC_26757646254573 — single-launch version.
//
// Analytical structure: out_b = exp(f1_b + i*f2_b) with
//   f_b = D[idx_last, idx_b] if idx_last < 8, else 0.
// setup_inputs() forces x[-1] = |x[-1]|+1 > 0 -> idx_last == 255 >= 8 ->
// c_shadow == 0 -> out == 1+0i everywhere. idx_last is still computed from x
// on device every call; the general path (idx_last < 8) is implemented as a
// per-block-redundant fp64 fallback so there is NO inter-block dependency
// (dispatch order / XCD coherence safe), it just never runs with live inputs.

#define NQ 8
#define NL 6
#define QDIM 256
#define BATCH 16384

// per-block workspace slice layout (doubles):
//   U: 131072, T: 131072, R: 131072, v: 2*256
#define OFF_U 0
#define OFF_T 131072
#define OFF_R 262144
#define OFF_V 393216
#define SLICE_DOUBLES 393728  // 393216 + 512

__device__ __forceinline__ int compute_idx(const float* __restrict__ xrow) {
  int v = 0;
#pragma unroll
  for (int j = 0; j < NQ; ++j)
    v |= (xrow[j] > 0.0f) ? (1 << (NQ - 1 - j)) : 0;
  return v;
}

// Full fp64 fallback, executed per-block (redundantly) only when idxl < 8.
// Thread t owns row t of U. Writes v[2][256] into this block's slice.
__device__ void heavy_path(
    int t, int idxl,
    const float* __restrict__ qx1, const float* __restrict__ qz1,
    const float* __restrict__ qx2, const float* __restrict__ qz2,
    double* __restrict__ W)
{
  double* U = W + OFF_U;
  double* T = W + OFF_T;
  double* R = W + OFF_R;
  const double ainv = 0.8705505632961241;  // 2^-0.2

  for (int circ = 0; circ < 2; ++circ) {
    const float* qx = circ ? qx2 : qx1;
    const float* qz = circ ? qz2 : qz1;

    for (int c = 0; c < QDIM; ++c) {
      U[((size_t)t * QDIM + c) * 2 + 0] = (c == t) ? 1.0 : 0.0;
      U[((size_t)t * QDIM + c) * 2 + 1] = 0.0;
    }

    for (int l = 0; l < NL; ++l) {
      double Mr[NQ][2][2], Mi[NQ][2][2];
      for (int j = 0; j < NQ; ++j) {
        double hx = 0.5 * (double)qx[l * NQ + j];
        double hz = 0.5 * (double)qz[l * NQ + j];
        double cx = cos(hx), sx = sin(hx), cz = cos(hz), sz = sin(hz);
        Mr[j][0][0] =  cx * cz;  Mi[j][0][0] =  cx * sz;
        Mr[j][0][1] = -sx * sz;  Mi[j][0][1] =  sx * cz;
        Mr[j][1][0] =  sx * sz;  Mi[j][1][0] =  sx * cz;
        Mr[j][1][1] =  cx * cz;  Mi[j][1][1] = -cx * sz;
      }

      __syncthreads();  // done reading previous R
      for (int c = 0; c < QDIM; ++c) {
        double ar = 1.0, ai = 0.0;
        for (int j = 0; j < NQ; ++j) {
          int rb = (t >> (NQ - 1 - j)) & 1;
          int cb = (c >> (NQ - 1 - j)) & 1;
          double br = Mr[j][rb][cb], bi = Mi[j][rb][cb];
          double nr = ar * br - ai * bi;
          ai = ar * bi + ai * br;
          ar = nr;
        }
        R[((size_t)t * QDIM + c) * 2 + 0] = ar;
        R[((size_t)t * QDIM + c) * 2 + 1] = ai;
      }
      __syncthreads();  // R built

      for (int n = 0; n < NQ - 1; ++n) {
        // U = U @ C_n (column op, row-local)
        const int bn = NQ - 1 - n;
        const int fm = 1 << (NQ - 2 - n);
        for (int c = 0; c < QDIM; ++c) {
          size_t pc = ((size_t)t * QDIM + c) * 2;
          if (((c >> bn) & 1) == 0) {
            U[pc + 0] *= ainv;
            U[pc + 1] *= ainv;
          } else if ((c & fm) == 0) {
            int c2 = c | fm;
            size_t p2 = ((size_t)t * QDIM + c2) * 2;
            double ar = U[pc + 0], ai = U[pc + 1];
            double br = U[p2 + 0], bi = U[p2 + 1];
            U[pc + 0] = (ar - 2.0 * ai + 2.0 * bi) * ainv;
            U[pc + 1] = (ai + 2.0 * ar - 2.0 * br) * ainv;
            U[p2 + 0] = (br - 2.0 * bi + 2.0 * ai) * ainv;
            U[p2 + 1] = (bi + 2.0 * br - 2.0 * ar) * ainv;
          }
        }
        // U = U @ R (dense row t)
        for (int c = 0; c < QDIM; ++c) {
          double ar = 0.0, ai = 0.0;
          for (int k = 0; k < QDIM; ++k) {
            double ur = U[((size_t)t * QDIM + k) * 2 + 0];
            double ui = U[((size_t)t * QDIM + k) * 2 + 1];
            double rr = R[((size_t)k * QDIM + c) * 2 + 0];
            double ri = R[((size_t)k * QDIM + c) * 2 + 1];
            ar += ur * rr - ui * ri;
            ai += ur * ri + ui * rr;
          }
          T[((size_t)t * QDIM + c) * 2 + 0] = ar;
          T[((size_t)t * QDIM + c) * 2 + 1] = ai;
        }
        for (int c = 0; c < QDIM; ++c) {
          U[((size_t)t * QDIM + c) * 2 + 0] = T[((size_t)t * QDIM + c) * 2 + 0];
          U[((size_t)t * QDIM + c) * 2 + 1] = T[((size_t)t * QDIM + c) * 2 + 1];
        }
      }
    }

    // U @ H, H[k][c] = (1/16)*(-1)^popc(k&c)
    for (int c = 0; c < QDIM; ++c) {
      double ar = 0.0, ai = 0.0;
      for (int k = 0; k < QDIM; ++k) {
        double s = (__popc(k & c) & 1) ? -1.0 : 1.0;
        ar += U[((size_t)t * QDIM + k) * 2 + 0] * s;
        ai += U[((size_t)t * QDIM + k) * 2 + 1] * s;
      }
      T[((size_t)t * QDIM + c) * 2 + 0] = ar * 0.0625;
      T[((size_t)t * QDIM + c) * 2 + 1] = ai * 0.0625;
    }
    __syncthreads();  // T built

    {
      double acc = 0.0;
      for (int m = 0; m < QDIM; ++m) {
        double s = ((m >> (NQ - 1 - idxl)) & 1) ? -1.0 : 1.0;
        double re = T[((size_t)m * QDIM + t) * 2 + 0];
        double im = T[((size_t)m * QDIM + t) * 2 + 1];
        acc += s * (re * re + im * im);
      }
      W[OFF_V + circ * QDIM + t] = acc;
    }
    __syncthreads();  // done reading T before next circuit
  }
  __syncthreads();  // v visible to whole block before output phase
}

// One launch: nblocks × 256. Each thread writes `per_thread` complex values.
__global__ __launch_bounds__(256) void fused_kernel(
    const float* __restrict__ x,
    const float* __restrict__ qx1, const float* __restrict__ qz1,
    const float* __restrict__ qx2, const float* __restrict__ qz2,
    double* __restrict__ Wbase,
    float* __restrict__ out, int n_complex, int interleaved, int per_thread)
{
  const int t = threadIdx.x;
  const int idxl = compute_idx(x + (size_t)(BATCH - 1) * NQ);

  double* W = Wbase + (size_t)blockIdx.x * SLICE_DOUBLES;
  const bool general = (idxl < NQ);
  if (general)
    heavy_path(t, idxl, qx1, qz1, qx2, qz2, W);

  const int base = (blockIdx.x * blockDim.x + t) * per_thread;

  if (!general && interleaved && per_thread == 4 && base + 4 <= n_complex &&
      (((uintptr_t)out) & 15) == 0) {
    // live fast path: 4 complex = two float4 stores of (1,0,1,0)
    float4 v; v.x = 1.0f; v.y = 0.0f; v.z = 1.0f; v.w = 0.0f;
    float4* o4 = reinterpret_cast<float4*>(out) + base / 2;
    o4[0] = v;
    o4[1] = v;
    return;
  }

  for (int r = 0; r < per_thread; ++r) {
    int b = base + r;
    if (b >= n_complex) break;
    float re = 1.0f, im = 0.0f;
    if (general) {
      const int ib = compute_idx(x + (size_t)b * NQ);
      double f1 = W[OFF_V + 0 * QDIM + ib];
      double f2 = W[OFF_V + 1 * QDIM + ib];
      double e = exp(f1);
      re = (float)(e * cos(f2));
      im = (float)(e * sin(f2));
    }
    if (interleaved) {
      float2 v; v.x = re; v.y = im;
      reinterpret_cast<float2*>(out)[b] = v;
    } else {
      out[b] = re;
    }
  }
}

extern "C" void kernel_launch(void* const* d_in, const int* in_sizes, int n_in,
                              void* d_out, int out_size, void* d_ws, size_t ws_size,
                              hipStream_t stream) {
  const float* x   = (const float*)d_in[0];
  const float* qx1 = (const float*)d_in[1];
  const float* qz1 = (const float*)d_in[2];
  const float* qx2 = (const float*)d_in[3];
  const float* qz2 = (const float*)d_in[4];
  // d_in[5]/d_in[6] (c1,c2) are dead in the reference (_f ignores c_embed)

  double* W  = (double*)d_ws;
  float* out = (float*)d_out;

  const int interleaved = (out_size == 2 * BATCH) ? 1 : 0;
  const int n = interleaved ? (out_size / 2) : out_size;

  // Each block needs its own fallback slice; cap block count by ws capacity.
  const size_t slice_bytes = (size_t)SLICE_DOUBLES * sizeof(double);
  int max_blocks = (int)(ws_size / slice_bytes);
  if (max_blocks < 1) max_blocks = 1;  // ws_size is known >= one slice (3.2 MB)
  int nblocks = 16 < max_blocks ? 16 : max_blocks;
  int per_thread = (n + nblocks * 256 - 1) / (nblocks * 256);

  fused_kernel<<<nblocks, 256, 0, stream>>>(x, qx1, qz1, qx2, qz2, W, out,
                                            n, interleaved, per_thread);
}